// Round 6
// baseline (474.776 us; speedup 1.0000x reference)
//
#include <hip/hip_runtime.h>
#include <math.h>

#define HH    48
#define CFEAT 512
#define HID   256
#define NPOS  (HH*HH)   // 2304
#define TQ    32        // queries per block
#define NEV   128       // evals per block = TQ*4
#define ACTP  264       // padded act row (bf16): 528B stride, rows 16B-aligned

typedef __attribute__((ext_vector_type(8))) short bf16x8;
typedef __attribute__((ext_vector_type(4))) float f32x4;

static __device__ __forceinline__ unsigned short f2bf(float x) {
  unsigned int u = __float_as_uint(x);
  u += 0x7fffu + ((u >> 16) & 1u);     // RNE
  return (unsigned short)(u >> 16);
}
static __device__ __forceinline__ float bf2f(unsigned short h) {
  return __uint_as_float(((unsigned int)h) << 16);
}

// ---------------------------------------------------------------------------
// Kernel 1: P[b][pos][n] = b0[n] + sum_c feat[b][c][pos] * W0[c][n]  (fp32)
// ---------------------------------------------------------------------------
__global__ __launch_bounds__(256) void liif_precompute(
    const float* __restrict__ feat, const float* __restrict__ W0,
    const float* __restrict__ b0, float* __restrict__ P)
{
  int blk = blockIdx.x;                 // 0..1151
  int b   = blk / (NPOS/4);
  int p0  = (blk - b*(NPOS/4)) * 4;
  int n   = threadIdx.x;
  const float* f = feat + (size_t)b * CFEAT * NPOS + p0;
  float bias = b0[n];
  float a0 = bias, a1 = bias, a2 = bias, a3 = bias;
  #pragma unroll 4
  for (int c = 0; c < CFEAT; ++c) {
    float w = W0[c*HID + n];
    const float* fr = f + (size_t)c * NPOS;
    a0 += fr[0]*w; a1 += fr[1]*w; a2 += fr[2]*w; a3 += fr[3]*w;
  }
  float* Pp = P + ((size_t)b*NPOS + p0)*HID + n;
  Pp[0*HID] = a0; Pp[1*HID] = a1; Pp[2*HID] = a2; Pp[3*HID] = a3;
}

// ---------------------------------------------------------------------------
// Kernel 2: transpose+convert W1..W3 -> bf16 Wt[l][n][k]; W4 -> f32 W4t[o][k]
// ---------------------------------------------------------------------------
__global__ __launch_bounds__(256) void liif_convert(
    const float* __restrict__ W1, const float* __restrict__ W2,
    const float* __restrict__ W3, const float* __restrict__ W4,
    unsigned short* __restrict__ wt, float* __restrict__ w4t)
{
  int b = blockIdx.x, t = threadIdx.x;
  if (b < 768) {
    int l = b >> 8, n = b & 255;
    const float* W = (l == 0) ? W1 : (l == 1) ? W2 : W3;
    wt[l*65536 + n*256 + t] = f2bf(W[t*256 + n]);   // Wt[n][k] = W[k][n]
  } else {
    for (int o = 0; o < 3; ++o) w4t[o*256 + t] = W4[t*3 + o];
  }
}

// ---------------------------------------------------------------------------
// Kernel 3: fused main. 128 evals/block, 8 waves (2x4), wave = 64x64 tile.
// W from L2 (4 frags/kc), act from LDS (4 reads/kc) -> 16 MFMA/kc.
// Final layer fused into layer-3 accumulators (no Phase D LDS pass).
// ---------------------------------------------------------------------------

#define LDW(WT, KC, NT) \
  (*(const bf16x8*)&(WT)[(size_t)(nW + (NT)*16 + lr)*256 + (KC)*32 + lk*8])
#define LDA(KC, MT) \
  (*(const bf16x8*)&act[(m0 + (MT)*16 + lr)*ACTP + (KC)*32 + lk*8])
#define MF(A, B, C) __builtin_amdgcn_mfma_f32_16x16x32_bf16((A), (B), (C), 0, 0, 0)

// MFMA body for one layer: fills acc[16] (mt*4+nt), then syncs.
#define LAYER_MM(WT) do {                                                     \
    _Pragma("unroll")                                                         \
    for (int i_ = 0; i_ < 16; ++i_) acc[i_] = (f32x4){0.f, 0.f, 0.f, 0.f};    \
    _Pragma("unroll 2")                                                       \
    for (int kc_ = 0; kc_ < 8; ++kc_) {                                       \
      bf16x8 w0_ = LDW(WT, kc_, 0), w1_ = LDW(WT, kc_, 1);                    \
      bf16x8 w2_ = LDW(WT, kc_, 2), w3_ = LDW(WT, kc_, 3);                    \
      bf16x8 a0_ = LDA(kc_, 0), a1_ = LDA(kc_, 1);                            \
      bf16x8 a2_ = LDA(kc_, 2), a3_ = LDA(kc_, 3);                            \
      acc[0]  = MF(w0_, a0_, acc[0]);  acc[1]  = MF(w1_, a0_, acc[1]);        \
      acc[2]  = MF(w2_, a0_, acc[2]);  acc[3]  = MF(w3_, a0_, acc[3]);        \
      acc[4]  = MF(w0_, a1_, acc[4]);  acc[5]  = MF(w1_, a1_, acc[5]);        \
      acc[6]  = MF(w2_, a1_, acc[6]);  acc[7]  = MF(w3_, a1_, acc[7]);        \
      acc[8]  = MF(w0_, a2_, acc[8]);  acc[9]  = MF(w1_, a2_, acc[9]);        \
      acc[10] = MF(w2_, a2_, acc[10]); acc[11] = MF(w3_, a2_, acc[11]);       \
      acc[12] = MF(w0_, a3_, acc[12]); acc[13] = MF(w1_, a3_, acc[13]);       \
      acc[14] = MF(w2_, a3_, acc[14]); acc[15] = MF(w3_, a3_, acc[15]);       \
    }                                                                         \
    __syncthreads();  /* all act reads of this layer done */                  \
  } while (0)

// bias+relu -> bf16 writeback to act (D[n][m]: lane m-col = lr, n = lk*4+j)
#define LAYER_WB(BIAS) do {                                                   \
    _Pragma("unroll")                                                         \
    for (int nt_ = 0; nt_ < 4; ++nt_) {                                       \
      f32x4 bv_ = *(const f32x4*)&(BIAS)[nW + nt_*16 + lk*4];                 \
      _Pragma("unroll")                                                       \
      for (int mt_ = 0; mt_ < 4; ++mt_) {                                     \
        f32x4 a_ = acc[mt_*4 + nt_];                                          \
        unsigned int lo_ = (unsigned int)f2bf(fmaxf(a_[0] + bv_[0], 0.f))     \
                         | ((unsigned int)f2bf(fmaxf(a_[1] + bv_[1], 0.f)) << 16); \
        unsigned int hi_ = (unsigned int)f2bf(fmaxf(a_[2] + bv_[2], 0.f))     \
                         | ((unsigned int)f2bf(fmaxf(a_[3] + bv_[3], 0.f)) << 16); \
        *(uint2*)&act[(m0 + mt_*16 + lr)*ACTP + nW + nt_*16 + lk*4] =         \
            make_uint2(lo_, hi_);                                             \
      }                                                                       \
    }                                                                         \
    __syncthreads();  /* writeback visible before next layer's reads */      \
  } while (0)

__global__ __launch_bounds__(512, 4)
__attribute__((amdgpu_waves_per_eu(4, 4)))
void liif_main(
    const float* __restrict__ coord, const float* __restrict__ cell,
    const float* __restrict__ P,  const float* __restrict__ W0,
    const unsigned short* __restrict__ wt,
    const float* __restrict__ b1, const float* __restrict__ b2,
    const float* __restrict__ b3, const float* __restrict__ b4,
    const float* __restrict__ w4t, float* __restrict__ out)
{
  __shared__ __align__(16) unsigned short act[NEV*ACTP];   // 67.6 KB
  __shared__ int   lin_s[NEV];
  __shared__ float r0_s[NEV], r1_s[NEV], rc0_s[NEV], rc1_s[NEV], area_s[NEV];
  float* predp = (float*)act;           // overlay: [4 wc][128 m][3 o] = 6 KB

  const int t   = threadIdx.x;
  const int blk = blockIdx.x;
  const int b   = blk >> 11;            // 2048 blocks per batch
  const int q0  = (blk & 2047) * TQ;

  const int lane = t & 63;
  const int w    = t >> 6;              // 0..7
  const int m0   = (w >> 2) * 64;       // wave row base (0 / 64)
  const int nW   = (w & 3) * 64;        // wave col base (0/64/128/192)
  const int lr   = lane & 15;
  const int lk   = lane >> 4;

  // ---- Phase A: indices, rel coords, areas (bit-exact vs numpy fp32) ------
  if (t < NEV) {
    const int e = t;
    const int q = q0 + (e >> 2);
    const int s = e & 3;                // [(-1,-1),(-1,1),(1,-1),(1,1)]
    const size_t cbase = (((size_t)b << 16) + q) * 2;
    float c0 = coord[cbase + 0];
    float c1 = coord[cbase + 1];
    float vx = (s & 2) ? 1.0f : -1.0f;
    float vy = (s & 1) ? 1.0f : -1.0f;
    const float RXY = (float)(1.0/48.0);
    const float CLO = (float)(-1.0 + 1e-6);
    const float CHI = (float)( 1.0 - 1e-6);
    float gx = __fadd_rn(c0, __fadd_rn(__fmul_rn(vx, RXY), 1e-6f));
    float gy = __fadd_rn(c1, __fadd_rn(__fmul_rn(vy, RXY), 1e-6f));
    gx = fminf(fmaxf(gx, CLO), CHI);
    gy = fminf(fmaxf(gy, CLO), CHI);
    float xr = __fmul_rn(__fsub_rn(__fmul_rn(__fadd_rn(gx, 1.0f), 48.0f), 1.0f), 0.5f);
    float xc = __fmul_rn(__fsub_rn(__fmul_rn(__fadd_rn(gy, 1.0f), 48.0f), 1.0f), 0.5f);
    int ir = (int)rintf(xr); ir = ir < 0 ? 0 : (ir > HH-1 ? HH-1 : ir);
    int ic = (int)rintf(xc); ic = ic < 0 ? 0 : (ic > HH-1 ? HH-1 : ic);
    lin_s[e] = ir*HH + ic;
    const float T2 = (float)(2.0/48.0);
    float qcr = __fsub_rn(__fmul_rn(__fadd_rn((float)ir, 0.5f), T2), 1.0f);
    float qcc = __fsub_rn(__fmul_rn(__fadd_rn((float)ic, 0.5f), T2), 1.0f);
    float r0 = __fmul_rn(__fsub_rn(c0, qcr), 48.0f);
    float r1 = __fmul_rn(__fsub_rn(c1, qcc), 48.0f);
    r0_s[e] = r0; r1_s[e] = r1;
    area_s[e] = __fadd_rn(fabsf(__fmul_rn(r0, r1)), 1e-9f);
    rc0_s[e] = __fmul_rn(cell[cbase + 0], 48.0f);
    rc1_s[e] = __fmul_rn(cell[cbase + 1], 48.0f);
  }
  __syncthreads();

  // ---- Phase B: h0 -> bf16 act. 512 thr: 128 col-pairs x 4 row-quarters ---
  {
    const int c2 = (t & 127) * 2;       // column pair
    const int rq = t >> 7;              // row quarter
    float wA = W0[(size_t)512*HID + c2],  wBv = W0[(size_t)512*HID + c2 + 1];
    float xA = W0[(size_t)513*HID + c2],  xB = W0[(size_t)513*HID + c2 + 1];
    float yA = W0[(size_t)514*HID + c2],  yB = W0[(size_t)514*HID + c2 + 1];
    float zA = W0[(size_t)515*HID + c2],  zB = W0[(size_t)515*HID + c2 + 1];
    const float* Pb = P + (size_t)b * NPOS * HID;
    #pragma unroll 4
    for (int i = 0; i < 32; ++i) {
      const int e = rq*32 + i;
      const float* pr = Pb + (size_t)lin_s[e]*HID + c2;
      float vA = pr[0] + r0_s[e]*wA + r1_s[e]*xA + rc0_s[e]*yA + rc1_s[e]*zA;
      float vB = pr[1] + r0_s[e]*wBv + r1_s[e]*xB + rc0_s[e]*yB + rc1_s[e]*zB;
      unsigned int pk = (unsigned int)f2bf(fmaxf(vA, 0.0f)) |
                        ((unsigned int)f2bf(fmaxf(vB, 0.0f)) << 16);
      *(unsigned int*)&act[e*ACTP + c2] = pk;
    }
  }
  __syncthreads();                      // act (h0) ready

  f32x4 acc[16];
  LAYER_MM(wt);              LAYER_WB(b1);   // layer 1
  LAYER_MM(wt + 65536);      LAYER_WB(b2);   // layer 2
  LAYER_MM(wt + 131072);                     // layer 3 (ends with barrier)

  // ---- fused final layer: p[mt][o] = sum_n relu(acc+b3) * W4t[o][n] -------
  {
    float p[4][3];
    #pragma unroll
    for (int mt = 0; mt < 4; ++mt)
      { p[mt][0] = 0.f; p[mt][1] = 0.f; p[mt][2] = 0.f; }
    #pragma unroll
    for (int nt = 0; nt < 4; ++nt) {
      f32x4 bv = *(const f32x4*)&b3[nW + nt*16 + lk*4];
      f32x4 w40 = *(const f32x4*)&w4t[      nW + nt*16 + lk*4];
      f32x4 w41 = *(const f32x4*)&w4t[256 + nW + nt*16 + lk*4];
      f32x4 w42 = *(const f32x4*)&w4t[512 + nW + nt*16 + lk*4];
      #pragma unroll
      for (int mt = 0; mt < 4; ++mt) {
        f32x4 a = acc[mt*4 + nt];
        #pragma unroll
        for (int j = 0; j < 4; ++j) {
          float v = fmaxf(a[j] + bv[j], 0.f);
          p[mt][0] += v * w40[j];
          p[mt][1] += v * w41[j];
          p[mt][2] += v * w42[j];
        }
      }
    }
    // reduce over lk groups (lanes 16/32 apart hold other n-subranges)
    #pragma unroll
    for (int mt = 0; mt < 4; ++mt)
      #pragma unroll
      for (int o = 0; o < 3; ++o) {
        float s = p[mt][o];
        s += __shfl_xor(s, 16);
        s += __shfl_xor(s, 32);
        p[mt][o] = s;
      }
    if (lk == 0) {                       // lanes 0..15: one writer per m-col
      #pragma unroll
      for (int mt = 0; mt < 4; ++mt) {
        const int m = m0 + mt*16 + lr;
        predp[(w & 3)*384 + m*3 + 0] = p[mt][0];
        predp[(w & 3)*384 + m*3 + 1] = p[mt][1];
        predp[(w & 3)*384 + m*3 + 2] = p[mt][2];
      }
    }
  }
  __syncthreads();

  // ---- blend: pred[e][o] = b4 + sum_wc partials; w[s] = area[3-s]/tot -----
  if (t < TQ*3) {
    const int q = t / 3, o = t - (t/3)*3;
    const int eb = q*4;
    float pe[4];
    #pragma unroll
    for (int s = 0; s < 4; ++s) {
      const int e = eb + s;
      pe[s] = b4[o] + predp[e*3 + o] + predp[384 + e*3 + o]
                    + predp[768 + e*3 + o] + predp[1152 + e*3 + o];
    }
    float a0 = area_s[eb+0], a1 = area_s[eb+1], a2 = area_s[eb+2], a3 = area_s[eb+3];
    float tot = ((a0 + a1) + a2) + a3;
    float rv = (pe[0]*a3 + pe[1]*a2 + pe[2]*a1 + pe[3]*a0) / tot;
    out[(((size_t)b << 16) + (q0 + q))*3 + o] = rv;
  }
}

// ---------------------------------------------------------------------------
extern "C" void kernel_launch(void* const* d_in, const int* in_sizes, int n_in,
                              void* d_out, int out_size, void* d_ws, size_t ws_size,
                              hipStream_t stream)
{
  const float* feat  = (const float*)d_in[0];
  const float* coord = (const float*)d_in[1];
  const float* cell  = (const float*)d_in[2];
  const float* W0    = (const float*)d_in[3];
  const float* b0    = (const float*)d_in[4];
  const float* W1    = (const float*)d_in[5];
  const float* b1    = (const float*)d_in[6];
  const float* W2    = (const float*)d_in[7];
  const float* b2    = (const float*)d_in[8];
  const float* W3    = (const float*)d_in[9];
  const float* b3    = (const float*)d_in[10];
  const float* W4    = (const float*)d_in[11];
  const float* b4    = (const float*)d_in[12];
  float* outp = (float*)d_out;

  // ws layout: P f32 [2*2304*256] = 4,718,592 B | Wt bf16 3*64K = 393,216 B
  //            | W4t f32 3*256 = 3,072 B
  float*          P    = (float*)d_ws;
  unsigned short* wtp  = (unsigned short*)((char*)d_ws + 4718592);
  float*          w4tp = (float*)((char*)d_ws + 4718592 + 393216);

  hipLaunchKernelGGL(liif_precompute, dim3(2*(NPOS/4)), dim3(256), 0, stream,
                     feat, W0, b0, P);
  hipLaunchKernelGGL(liif_convert, dim3(769), dim3(256), 0, stream,
                     W1, W2, W3, W4, wtp, w4tp);
  hipLaunchKernelGGL(liif_main, dim3(4096), dim3(512), 0, stream,
                     coord, cell, P, W0, wtp, b1, b2, b3, b4, w4tp, outp);
}